// Round 1
// baseline (308.564 us; speedup 1.0000x reference)
//
#include <hip/hip_runtime.h>

#define BIGF 1e10f
#define HH 256
#define WW 256
#define BB 4
#define NPIX (BB * HH * WW) // 262144 elements per image

// ws layout (bytes):
//   [0   .. 31 ]  int flags[8]   : pred_any[4], target_any[4]
//   [64  .. 71 ]  double acc
//   [128 .. 128 + 4*BB*HH*WW*4)  float F1[4][BB][HH][WW]  (pass-1 output)
#define WS_FLAGS_OFF 0
#define WS_ACC_OFF 64
#define WS_F1_OFF 128

__global__ void hdt_flags_kernel(const float* __restrict__ pred,
                                 const float* __restrict__ tgt,
                                 int* __restrict__ flags) {
    // grid = 8 blocks: blockIdx.x = img*4 + b
    int img = blockIdx.x >> 2;
    int b = blockIdx.x & 3;
    const float* base = (img ? tgt : pred) + b * (HH * WW);
    bool any = false;
    for (int i = threadIdx.x; i < HH * WW; i += blockDim.x)
        any |= (base[i] > 0.5f);
    unsigned long long bal = __ballot(any);
    __shared__ int s_any;
    if (threadIdx.x == 0) s_any = 0;
    __syncthreads();
    if ((threadIdx.x & 63) == 0 && bal != 0ULL) atomicOr(&s_any, 1);
    __syncthreads();
    if (threadIdx.x == 0) flags[img * 4 + b] = s_any;
}

// Pass 1: min-plus EDT along W for all 4 fields (pred_fg, pred_bg, tgt_fg, tgt_bg)
__global__ void hdt_pass1_kernel(const float* __restrict__ pred,
                                 const float* __restrict__ tgt,
                                 float* __restrict__ F1) {
    // blockIdx.x = ((field*BB + b) * HH + y), threadIdx.x = x
    int blk = blockIdx.x;
    int y = blk & (HH - 1);
    int fb = blk >> 8;
    int b = fb & (BB - 1);
    int field = fb >> 2;
    int img = field >> 1;  // 0=pred 1=target
    int inv = field & 1;   // 0=fg   1=~fg
    const float* src = (img ? tgt : pred) + b * (HH * WW) + y * WW;
    int x = threadIdx.x;
    bool fg = src[x] > 0.5f;
    bool m = inv ? !fg : fg;
    __shared__ float fz[WW];
    fz[x] = m ? BIGF : 0.0f;
    __syncthreads();
    float xf = (float)x;
    float mn = fz[x]; // j == x candidate, par = 0 (keeps all-BIG rows exactly BIG)
    #pragma unroll 8
    for (int j = 0; j < WW; ++j) {
        float d = xf - (float)j;
        mn = fminf(mn, fz[j] + d * d);
    }
    F1[blk * WW + x] = mn;
}

// Pass 2 along H + fused loss reduction.
__global__ void hdt_pass2_reduce_kernel(const float* __restrict__ pred,
                                        const float* __restrict__ tgt,
                                        const float* __restrict__ F1,
                                        const int* __restrict__ flags,
                                        double* __restrict__ acc) {
    // blockIdx.x = b*WW + x, threadIdx.x = y
    int blk = blockIdx.x;
    int x = blk & (WW - 1);
    int b = blk >> 8;
    int y = threadIdx.x;
    __shared__ float fz[4][HH];
    #pragma unroll
    for (int f = 0; f < 4; ++f)
        fz[f][y] = F1[((f * BB + b) * HH + y) * WW + x];
    __syncthreads();
    float v[4];
    float yf = (float)y;
    #pragma unroll
    for (int f = 0; f < 4; ++f) {
        float mn = fz[f][y];
        #pragma unroll 8
        for (int i = 0; i < HH; ++i) {
            float d = yf - (float)i;
            mn = fminf(mn, fz[f][i] + d * d);
        }
        v[f] = mn;
    }
    int idx = b * (HH * WW) + y * WW + x;
    float pv = pred[idx], tv = tgt[idx];
    float dtp = 0.0f, dtt = 0.0f;
    if (flags[b])     dtp = sqrtf(fminf(v[0], BIGF)) + sqrtf(fminf(v[1], BIGF));
    if (flags[4 + b]) dtt = sqrtf(fminf(v[2], BIGF)) + sqrtf(fminf(v[3], BIGF));
    float e = pv - tv;
    float term = e * e * (dtp * dtp + dtt * dtt);

    // wave reduce (wave64), then cross-wave via LDS
    #pragma unroll
    for (int off = 32; off > 0; off >>= 1)
        term += __shfl_down(term, off, 64);
    __shared__ float wsum[4];
    int lane = threadIdx.x & 63;
    int wid = threadIdx.x >> 6;
    if (lane == 0) wsum[wid] = term;
    __syncthreads();
    if (threadIdx.x == 0) {
        float s = wsum[0] + wsum[1] + wsum[2] + wsum[3];
        atomicAdd(acc, (double)s);
    }
}

__global__ void hdt_finalize_kernel(const double* __restrict__ acc,
                                    float* __restrict__ out) {
    out[0] = (float)(acc[0] * (1.0 / (double)NPIX));
}

extern "C" void kernel_launch(void* const* d_in, const int* in_sizes, int n_in,
                              void* d_out, int out_size, void* d_ws, size_t ws_size,
                              hipStream_t stream) {
    const float* pred = (const float*)d_in[0];
    const float* tgt = (const float*)d_in[1];
    float* out = (float*)d_out;
    char* ws = (char*)d_ws;
    int* flags = (int*)(ws + WS_FLAGS_OFF);
    double* acc = (double*)(ws + WS_ACC_OFF);
    float* F1 = (float*)(ws + WS_F1_OFF);

    // zero flags + accumulator (ws is poisoned 0xAA before every timed launch)
    hipMemsetAsync(ws, 0, 128, stream);

    hdt_flags_kernel<<<8, 256, 0, stream>>>(pred, tgt, flags);
    hdt_pass1_kernel<<<4 * BB * HH, WW, 0, stream>>>(pred, tgt, F1);
    hdt_pass2_reduce_kernel<<<BB * WW, HH, 0, stream>>>(pred, tgt, F1, flags, acc);
    hdt_finalize_kernel<<<1, 1, 0, stream>>>(acc, out);
}

// Round 2
// 92.404 us; speedup vs baseline: 3.3393x; 3.3393x over previous
//
#include <hip/hip_runtime.h>

#define BIGF 1e10f
#define HH 256
#define WW 256
#define BB 4
#define NPIX (BB * HH * WW)

// ws layout (bytes):
//   [0 .. 31]   int flags[8] : pred_any[4], target_any[4]
//   [64 .. 71]  double acc
//   [128 .. 128 + 4*BB*HH*WW*2)  u16 F1u[4][BB][HH][WW]  (pass-1 squared dists, 0xFFFF = BIG)
#define WS_FLAGS_OFF 0
#define WS_ACC_OFF 64
#define WS_F1_OFF 128

// nearest set bit distance in a 256-bit mask (words M[0..3], bit p = 64w+lane),
// searching both directions from x. Returns > 255 if mask empty.
__device__ inline int nearest_set_dist(const unsigned long long* M, int x) {
    int wx = x >> 6, bx = x & 63;
    int dl = 1 << 20, dr = 1 << 20;
    // left: highest set bit p <= x
    unsigned long long t = M[wx] & (bx == 63 ? ~0ULL : ((1ULL << (bx + 1)) - 1ULL));
    int w = wx;
    while (true) {
        if (t) { int p = (w << 6) + 63 - __builtin_clzll(t); dl = x - p; break; }
        if (--w < 0) break;
        t = M[w];
    }
    // right: lowest set bit p >= x
    t = M[wx] & (~0ULL << bx);
    w = wx;
    while (true) {
        if (t) { int p = (w << 6) + __builtin_ctzll(t); dr = p - x; break; }
        if (++w > 3) break;
        t = M[w];
    }
    return dl < dr ? dl : dr;
}

// Kernel A: per-(img,b,y) row. Ballot the fg mask, compute exact 1D EDT^2 along W
// for both fg and ~fg fields via bit scans; also atomicOr the per-(img,b) any-fg flag.
__global__ void hdt_rows_kernel(const float* __restrict__ pred,
                                const float* __restrict__ tgt,
                                unsigned short* __restrict__ F1u,
                                int* __restrict__ flags) {
    int blk = blockIdx.x;          // (img*4 + b)*256 + y
    int y = blk & (HH - 1);
    int b = (blk >> 8) & 3;
    int img = blk >> 10;
    const float* src = (img ? tgt : pred) + (b * HH + y) * WW;
    int x = threadIdx.x;
    bool fg = src[x] > 0.5f;
    unsigned long long bal = __ballot(fg);
    __shared__ unsigned long long mfg[4];
    if ((x & 63) == 0) mfg[x >> 6] = bal;
    __syncthreads();
    unsigned long long Mfg[4] = {mfg[0], mfg[1], mfg[2], mfg[3]};
    unsigned long long Mbg[4] = {~Mfg[0], ~Mfg[1], ~Mfg[2], ~Mfg[3]};
    if (x == 0 && (Mfg[0] | Mfg[1] | Mfg[2] | Mfg[3]))
        atomicOr(&flags[img * 4 + b], 1);
    // fg field: distance to nearest bg pixel; bg field: distance to nearest fg pixel
    int dbg = nearest_set_dist(Mbg, x);
    int dfg = nearest_set_dist(Mfg, x);
    unsigned short v_fg = (dbg > 255) ? (unsigned short)0xFFFFu
                                      : (unsigned short)(dbg * dbg);
    unsigned short v_bg = (dfg > 255) ? (unsigned short)0xFFFFu
                                      : (unsigned short)(dfg * dfg);
    int fbase = img * 2;
    F1u[(((fbase + 0) * BB + b) * HH + y) * WW + x] = v_fg;
    F1u[(((fbase + 1) * BB + b) * HH + y) * WW + x] = v_bg;
}

// Kernel B: per-(b, 8-column x-tile). Stage all 4 fields' column data through LDS
// (transposed, float), run the exact expanding-window min-plus along H per pixel,
// fuse the loss and block-reduce into one atomicAdd.
__launch_bounds__(1024)
__global__ void hdt_cols_loss_kernel(const float* __restrict__ pred,
                                     const float* __restrict__ tgt,
                                     const unsigned short* __restrict__ F1u,
                                     const int* __restrict__ flags,
                                     double* __restrict__ acc) {
    int blk = blockIdx.x;          // b*32 + xt
    int xt = blk & 31;
    int b = blk >> 5;
    int x0 = xt * 8;
    __shared__ float S[4][8][HH];  // [field][xi][y]  32 KB
    int tid = threadIdx.x;
    int f = tid >> 8, y = tid & (HH - 1);
    // load one uint4 = 8 u16 of row y, field f, columns x0..x0+7
    const uint4* rp = (const uint4*)(F1u + ((f * BB + b) * HH + y) * WW + x0);
    uint4 r = *rp;
    unsigned words[4] = {r.x, r.y, r.z, r.w};
    #pragma unroll
    for (int k = 0; k < 4; ++k) {
        unsigned lo = words[k] & 0xFFFFu, hi = words[k] >> 16;
        S[f][2 * k + 0][y] = (lo == 0xFFFFu) ? BIGF : (float)lo;
        S[f][2 * k + 1][y] = (hi == 0xFFFFu) ? BIGF : (float)hi;
    }
    __syncthreads();

    int xig = tid >> 8;            // 0..3 ; this thread handles xi = xig and xig+4
    float lsum = 0.0f;
    int fl_p = flags[b], fl_t = flags[4 + b];
    #pragma unroll
    for (int half = 0; half < 2; ++half) {
        int xi = xig + half * 4;
        float v4[4];
        #pragma unroll
        for (int ff = 0; ff < 4; ++ff) {
            const float* col = S[ff][xi];
            float best = col[y];   // s = 0 candidate
            for (int s = 1; s < HH; ++s) {
                float ss = (float)(s * s);
                if (ss >= best) break;   // farther candidates are >= s^2 >= best
                int ym = y - s, yp = y + s;
                if (ym >= 0)  best = fminf(best, col[ym] + ss);
                if (yp < HH)  best = fminf(best, col[yp] + ss);
            }
            v4[ff] = best;
        }
        int x = x0 + xi;
        int idx = (b * HH + y) * WW + x;
        float pv = pred[idx], tv = tgt[idx];
        float dtp = 0.0f, dtt = 0.0f;
        if (fl_p) dtp = sqrtf(fminf(v4[0], BIGF)) + sqrtf(fminf(v4[1], BIGF));
        if (fl_t) dtt = sqrtf(fminf(v4[2], BIGF)) + sqrtf(fminf(v4[3], BIGF));
        float e = pv - tv;
        lsum += e * e * (dtp * dtp + dtt * dtt);
    }

    // block reduce: wave64 shuffle then LDS across 16 waves
    #pragma unroll
    for (int off = 32; off > 0; off >>= 1)
        lsum += __shfl_down(lsum, off, 64);
    __shared__ float wsum[16];
    int lane = tid & 63, wv = tid >> 6;
    if (lane == 0) wsum[wv] = lsum;
    __syncthreads();
    if (tid == 0) {
        float s2 = 0.0f;
        #pragma unroll
        for (int i = 0; i < 16; ++i) s2 += wsum[i];
        atomicAdd(acc, (double)s2);
    }
}

__global__ void hdt_finalize_kernel(const double* __restrict__ acc,
                                    float* __restrict__ out) {
    out[0] = (float)(acc[0] * (1.0 / (double)NPIX));
}

extern "C" void kernel_launch(void* const* d_in, const int* in_sizes, int n_in,
                              void* d_out, int out_size, void* d_ws, size_t ws_size,
                              hipStream_t stream) {
    const float* pred = (const float*)d_in[0];
    const float* tgt = (const float*)d_in[1];
    float* out = (float*)d_out;
    char* ws = (char*)d_ws;
    int* flags = (int*)(ws + WS_FLAGS_OFF);
    double* acc = (double*)(ws + WS_ACC_OFF);
    unsigned short* F1u = (unsigned short*)(ws + WS_F1_OFF);

    hipMemsetAsync(ws, 0, 128, stream);  // zero flags + accumulator
    hdt_rows_kernel<<<2 * BB * HH, WW, 0, stream>>>(pred, tgt, F1u, flags);
    hdt_cols_loss_kernel<<<BB * 32, 1024, 0, stream>>>(pred, tgt, F1u, flags, acc);
    hdt_finalize_kernel<<<1, 1, 0, stream>>>(acc, out);
}